// Round 6
// baseline (133.019 us; speedup 1.0000x reference)
//
#include <hip/hip_runtime.h>
#include <hip/hip_cooperative_groups.h>

namespace cg = cooperative_groups;

#define BB 8
#define CC 512
#define NN 2048
#define SEM 32
#define BN_EPS 1e-5f
#define NCC 16
#define NCHUNK 32
#define KARR (BB * NCHUNK * NN)   // 524288 floats per projection array

struct Ptrs {
    const float *x, *gw, *tw, *pw, *gb, *tb, *pb;
    const float *se1w, *se1b, *se2w, *se2b, *Ww, *Wb, *gam, *bet, *mu, *var;
    float *pp, *avgp, *gx, *tx, *px, *y, *Ac, *Dc, *out;
};

// ============ P1: proj partials + avg partials ============
// 256 blocks = (b, cc). Block covers 16 channels x full 2048-px row.
// Thread owns one float2 pixel-pair; 16 loads in flight.
__device__ __forceinline__ void phase1(const Ptrs& p, int blk, int tid) {
    int b = blk >> 5, cc = blk & 31, c0 = cc * NCC;
    const float2* xp2 = reinterpret_cast<const float2*>(p.x)
                      + (size_t)(b * CC + c0) * (NN / 2) + tid;
    float2 v[NCC];
    #pragma unroll
    for (int c = 0; c < NCC; ++c) v[c] = xp2[c * (NN / 2)];

    float2 ag = {0,0}, at_ = {0,0}, ap = {0,0};
    float s[NCC];
    #pragma unroll
    for (int c = 0; c < NCC; ++c) {
        float wg = p.gw[c0 + c], wt = p.tw[c0 + c], wp = p.pw[c0 + c];
        ag.x  = fmaf(wg, v[c].x, ag.x);  ag.y  = fmaf(wg, v[c].y, ag.y);
        at_.x = fmaf(wt, v[c].x, at_.x); at_.y = fmaf(wt, v[c].y, at_.y);
        ap.x  = fmaf(wp, v[c].x, ap.x);  ap.y  = fmaf(wp, v[c].y, ap.y);
        s[c] = v[c].x + v[c].y;
    }

    size_t base = (size_t)blk * (NN / 2) + tid;   // blk == b*32+cc
    reinterpret_cast<float2*>(p.pp)[base] = ag;
    reinterpret_cast<float2*>(p.pp + KARR)[base] = at_;
    reinterpret_cast<float2*>(p.pp + 2 * (size_t)KARR)[base] = ap;

    #pragma unroll
    for (int o = 32; o > 0; o >>= 1) {
        #pragma unroll
        for (int c = 0; c < NCC; ++c) s[c] += __shfl_down(s[c], o);
    }
    int wave = tid >> 6, lane = tid & 63;
    if (lane == 0) {
        #pragma unroll
        for (int c = 0; c < NCC; ++c)
            p.avgp[(size_t)(b * CC + c0 + c) * 16 + wave] = s[c];
    }
}

// ============ P2: finalize gx/tx/px (blocks 0..63)  ||  SE/affine (blocks 64..71) ============
__device__ __forceinline__ void phase2(const Ptrs& p, int blk, int tid, float* smem) {
    if (blk < 64) {
        int b = blk >> 3, oct = blk & 7;
        int pxi = tid & 255, rep = tid >> 8;          // 4 reps x 8 chunks
        int pix = oct * 256 + pxi;
        const float* base0 = p.pp + (size_t)b * NCHUNK * NN + pix + (size_t)rep * 8 * NN;
        float a0 = 0.f, a1 = 0.f, a2 = 0.f;
        #pragma unroll
        for (int c = 0; c < 8; ++c) {
            a0 += base0[(size_t)c * NN];
            a1 += base0[(size_t)c * NN + KARR];
            a2 += base0[(size_t)c * NN + 2 * (size_t)KARR];
        }
        smem[rep * 256 + pxi]        = a0;
        smem[1024 + rep * 256 + pxi] = a1;
        smem[2048 + rep * 256 + pxi] = a2;
        __syncthreads();
        if (tid < 768) {
            int k = tid >> 8, px2 = tid & 255;
            float* sk = smem + k * 1024;
            float v = sk[px2] + sk[256 + px2] + sk[512 + px2] + sk[768 + px2];
            int o = b * NN + oct * 256 + px2;
            if (k == 0)      p.gx[o] = v;               // gb folded into Dc
            else if (k == 1) p.tx[o] = v + p.tb[0];
            else             p.px[o] = v + p.pb[0];
        }
    } else if (blk < 72) {
        int b = blk - 64;
        float* sA = smem;          // 512
        float* sP = smem + 512;    // 32*16
        float* sM = smem + 1024;   // 32
        if (tid < 512) {
            const float* apt = p.avgp + (size_t)(b * CC + tid) * 16;
            float ssum = 0.f;
            #pragma unroll
            for (int k = 0; k < 16; ++k) ssum += apt[k];
            sA[tid] = ssum * (1.0f / NN);
        }
        __syncthreads();
        if (tid < 512) {
            int m = tid >> 4, sub = tid & 15;
            const float* w1 = p.se1w + m * CC + sub * 32;
            const float* a1 = sA + sub * 32;
            float ssum = 0.f;
            #pragma unroll
            for (int k = 0; k < 32; ++k) ssum = fmaf(a1[k], w1[k], ssum);
            sP[m * 16 + sub] = ssum;
        }
        __syncthreads();
        if (tid < SEM) {
            float t = 0.f;
            #pragma unroll
            for (int k = 0; k < 16; ++k) t += sP[tid * 16 + k];
            sM[tid] = fmaxf(t + p.se1b[tid], 0.f);
        }
        __syncthreads();
        if (tid < 512) {
            int c = tid;
            float s2 = 0.f;
            #pragma unroll
            for (int m = 0; m < SEM; ++m) s2 = fmaf(sM[m], p.se2w[c * SEM + m], s2);
            s2 += p.se2b[c];
            float wcw = 1.f / (1.f + __expf(-s2));
            float inv = p.gam[c] * rsqrtf(p.var[c] + BN_EPS);
            float A = wcw * p.Ww[c] * inv;
            p.Ac[b * CC + c] = A;
            p.Dc[b * CC + c] = wcw * ((p.Wb[c] - p.mu[c]) * inv + p.bet[c]) + A * p.gb[0];
        }
    }
}

// ============ P3: rank-1 softmax y (no-max, clamped) ============
// 256 blocks = (b, 64-row group). 4 rows per wave.
__device__ __forceinline__ void phase3(const Ptrs& p, int blk, int tid, float* smem) {
    float2* pg = reinterpret_cast<float2*>(smem);
    int b = blk >> 5, rg = blk & 31;
    const float* pxr = p.px + b * NN;
    const float* gxr = p.gx + b * NN;
    #pragma unroll
    for (int j0 = 0; j0 < 2; ++j0) {
        int j = j0 * 1024 + tid;
        pg[j] = make_float2(pxr[j], gxr[j]);
    }
    __syncthreads();

    int wave = tid >> 6, lane = tid & 63;
    int r0 = rg * 64 + wave * 4;
    float t0 = p.tx[b * NN + r0 + 0];
    float t1 = p.tx[b * NN + r0 + 1];
    float t2 = p.tx[b * NN + r0 + 2];
    float t3 = p.tx[b * NN + r0 + 3];
    float s0 = 0.f, g0 = 0.f, s1 = 0.f, g1 = 0.f;
    float s2 = 0.f, g2 = 0.f, s3 = 0.f, g3 = 0.f;
    #pragma unroll 4
    for (int j = lane; j < NN; j += 64) {
        float2 v = pg[j];
        float e0 = __expf(fminf(t0 * v.x, 80.f));
        float e1 = __expf(fminf(t1 * v.x, 80.f));
        float e2 = __expf(fminf(t2 * v.x, 80.f));
        float e3 = __expf(fminf(t3 * v.x, 80.f));
        s0 += e0; g0 = fmaf(e0, v.y, g0);
        s1 += e1; g1 = fmaf(e1, v.y, g1);
        s2 += e2; g2 = fmaf(e2, v.y, g2);
        s3 += e3; g3 = fmaf(e3, v.y, g3);
    }
    for (int o = 32; o > 0; o >>= 1) {
        s0 += __shfl_down(s0, o); g0 += __shfl_down(g0, o);
        s1 += __shfl_down(s1, o); g1 += __shfl_down(g1, o);
        s2 += __shfl_down(s2, o); g2 += __shfl_down(g2, o);
        s3 += __shfl_down(s3, o); g3 += __shfl_down(g3, o);
    }
    if (lane == 0) {
        p.y[b * NN + r0 + 0] = g0 / s0;
        p.y[b * NN + r0 + 1] = g1 / s1;
        p.y[b * NN + r0 + 2] = g2 / s2;
        p.y[b * NN + r0 + 3] = g3 / s3;
    }
}

// ============ P4: epilogue out = A*y + D + x ============
// 256 blocks = 16 (b,c) rows each. Thread: 1 float4 column slot x 8 rows.
__device__ __forceinline__ void phase4(const Ptrs& p, int blk, int tid) {
    int bc0 = blk * 16;
    int b = blk >> 5;
    int f4 = tid & 511, rr = tid >> 9;
    float4 yv = reinterpret_cast<const float4*>(p.y + (size_t)b * NN)[f4];
    float av[8], dv[8];
    float4 xv[8];
    #pragma unroll
    for (int r = 0; r < 8; ++r) {
        int bc = bc0 + rr * 8 + r;
        av[r] = p.Ac[bc];
        dv[r] = p.Dc[bc];
        xv[r] = reinterpret_cast<const float4*>(p.x)[(size_t)bc * (NN / 4) + f4];
    }
    #pragma unroll
    for (int r = 0; r < 8; ++r) {
        int bc = bc0 + rr * 8 + r;
        float4 ov;
        ov.x = fmaf(av[r], yv.x, dv[r]) + xv[r].x;
        ov.y = fmaf(av[r], yv.y, dv[r]) + xv[r].y;
        ov.z = fmaf(av[r], yv.z, dv[r]) + xv[r].z;
        ov.w = fmaf(av[r], yv.w, dv[r]) + xv[r].w;
        reinterpret_cast<float4*>(p.out)[(size_t)bc * (NN / 4) + f4] = ov;
    }
}

// ============ kernels ============
__global__ __launch_bounds__(1024, 4) void kcoop(Ptrs p) {
    __shared__ float smem[4096];
    cg::grid_group g = cg::this_grid();
    int blk = blockIdx.x, tid = threadIdx.x;
    phase1(p, blk, tid);
    g.sync();
    phase2(p, blk, tid, smem);
    g.sync();
    phase3(p, blk, tid, smem);
    g.sync();
    phase4(p, blk, tid);
}

__global__ __launch_bounds__(1024, 4) void fb1(Ptrs p) { phase1(p, blockIdx.x, threadIdx.x); }
__global__ __launch_bounds__(1024, 4) void fb2(Ptrs p) {
    __shared__ float smem[4096];
    phase2(p, blockIdx.x, threadIdx.x, smem);
}
__global__ __launch_bounds__(1024, 4) void fb3(Ptrs p) {
    __shared__ float smem[4096];
    phase3(p, blockIdx.x, threadIdx.x, smem);
}
__global__ __launch_bounds__(1024, 4) void fb4(Ptrs p) { phase4(p, blockIdx.x, threadIdx.x); }

extern "C" void kernel_launch(void* const* d_in, const int* in_sizes, int n_in,
                              void* d_out, int out_size, void* d_ws, size_t ws_size,
                              hipStream_t stream) {
    Ptrs P;
    P.x    = (const float*)d_in[0];
    P.gw   = (const float*)d_in[1];
    P.gb   = (const float*)d_in[2];
    P.tw   = (const float*)d_in[3];
    P.tb   = (const float*)d_in[4];
    P.pw   = (const float*)d_in[5];
    P.pb   = (const float*)d_in[6];
    P.Ww   = (const float*)d_in[7];
    P.Wb   = (const float*)d_in[8];
    P.gam  = (const float*)d_in[9];
    P.bet  = (const float*)d_in[10];
    P.mu   = (const float*)d_in[11];
    P.var  = (const float*)d_in[12];
    P.se1w = (const float*)d_in[13];
    P.se1b = (const float*)d_in[14];
    P.se2w = (const float*)d_in[15];
    P.se2b = (const float*)d_in[16];

    float* ws = (float*)d_ws;
    P.pp   = ws; ws += 3 * (size_t)KARR;
    P.avgp = ws; ws += BB * CC * 16;
    P.gx   = ws; ws += BB * NN;
    P.tx   = ws; ws += BB * NN;
    P.px   = ws; ws += BB * NN;
    P.y    = ws; ws += BB * NN;
    P.Ac   = ws; ws += BB * CC;
    P.Dc   = ws; ws += BB * CC;
    P.out  = (float*)d_out;

    void* args[] = { (void*)&P };
    hipError_t err = hipLaunchCooperativeKernel(reinterpret_cast<void*>(kcoop),
                                                dim3(256), dim3(1024), args, 0, stream);
    if (err != hipSuccess) {
        (void)hipGetLastError();   // clear last-error, then multi-kernel fallback
        fb1<<<256, 1024, 0, stream>>>(P);
        fb2<<<72,  1024, 0, stream>>>(P);
        fb3<<<256, 1024, 0, stream>>>(P);
        fb4<<<256, 1024, 0, stream>>>(P);
    }
}

// Round 8
// 43.925 us; speedup vs baseline: 3.0283x; 3.0283x over previous
//
#include <hip/hip_runtime.h>

#define BB 8
#define CC 512
#define NN 2048
#define SEM 32
#define BN_EPS 1e-5f
#define LOG2E 1.4426950408889634f

#define CG 32                 // channels per group in K1
#define NG (CC / CG)          // 16 groups
#define KARR (NG * BB * NN)   // 262144 floats per projection partial array

// ---------------- K1: x pass -> proj partials (per 32-ch group) + avg partials ----------------
// grid = 256 blocks = (b:8, g:16, h:2). Block: 32 channels x 1024-px half-row.
__global__ __launch_bounds__(256) void k1(const float* __restrict__ x,
    const float* __restrict__ gw, const float* __restrict__ tw, const float* __restrict__ pw,
    float* __restrict__ pp, float* __restrict__ avgp)
{
    int tid = threadIdx.x;
    int wave = tid >> 6, lane = tid & 63;
    int blk = blockIdx.x;
    int h = blk & 1;
    int g = (blk >> 1) & (NG - 1);
    int b = blk >> 5;
    int c0 = g * CG;

    const float2* xp = reinterpret_cast<const float2*>(x)
                     + (size_t)(b * CC + c0) * (NN / 2) + h * 512 + tid;

    float2 ag0 = {0,0}, at0 = {0,0}, ap0 = {0,0};
    float2 ag1 = {0,0}, at1 = {0,0}, ap1 = {0,0};
    float s[CG];

    #pragma unroll 8
    for (int c = 0; c < CG; ++c) {
        float2 v0 = xp[(size_t)c * (NN / 2)];
        float2 v1 = xp[(size_t)c * (NN / 2) + 256];
        float wg = gw[c0 + c], wt = tw[c0 + c], wp = pw[c0 + c];
        ag0.x = fmaf(wg, v0.x, ag0.x); ag0.y = fmaf(wg, v0.y, ag0.y);
        at0.x = fmaf(wt, v0.x, at0.x); at0.y = fmaf(wt, v0.y, at0.y);
        ap0.x = fmaf(wp, v0.x, ap0.x); ap0.y = fmaf(wp, v0.y, ap0.y);
        ag1.x = fmaf(wg, v1.x, ag1.x); ag1.y = fmaf(wg, v1.y, ag1.y);
        at1.x = fmaf(wt, v1.x, at1.x); at1.y = fmaf(wt, v1.y, at1.y);
        ap1.x = fmaf(wp, v1.x, ap1.x); ap1.y = fmaf(wp, v1.y, ap1.y);
        s[c] = (v0.x + v0.y) + (v1.x + v1.y);
    }

    // pp[k][g][b][px] as float2
    size_t i0 = (size_t)(g * BB + b) * 1024 + h * 512 + tid;
    float2* pp2 = reinterpret_cast<float2*>(pp);
    pp2[i0]                  = ag0;
    pp2[i0 + 256]            = ag1;
    pp2[KARR / 2 + i0]       = at0;
    pp2[KARR / 2 + i0 + 256] = at1;
    pp2[KARR + i0]           = ap0;
    pp2[KARR + i0 + 256]     = ap1;

    #pragma unroll
    for (int o = 32; o > 0; o >>= 1) {
        #pragma unroll
        for (int c = 0; c < CG; ++c) s[c] += __shfl_down(s[c], o);
    }
    if (lane == 0) {
        #pragma unroll
        for (int c = 0; c < CG; ++c)
            avgp[(size_t)(b * CC + c0 + c) * 8 + h * 4 + wave] = s[c];
    }
}

// ---------------- K2: reduce 16 group-partials -> gx/tx/px ----------------
// grid = 192 blocks = (b:8, k:3, oct:8). blk = b*24 + k*8 + oct.
__global__ __launch_bounds__(256) void k2(
    const float* __restrict__ pp,
    const float* __restrict__ tb, const float* __restrict__ pb,
    float* __restrict__ gx, float* __restrict__ tx, float* __restrict__ px)
{
    int tid = threadIdx.x;
    int oct = blockIdx.x & 7;
    int g3  = blockIdx.x >> 3;     // 0..23
    int k   = g3 % 3;              // 0,1,2
    int b   = g3 / 3;              // 0..7
    int p   = oct * 256 + tid;
    const float* base = pp + (size_t)k * KARR + (size_t)b * NN + p;
    float v = 0.f;
    #pragma unroll
    for (int g = 0; g < NG; ++g)
        v += base[(size_t)g * BB * NN];
    int o = b * NN + p;
    if (k == 0)      gx[o] = v;              // gb folded into Dc
    else if (k == 1) tx[o] = v + tb[0];
    else             px[o] = v + pb[0];
}

// ---------------- K3: rank-1 softmax (exp2, no-max) + SE/affine ----------------
// grid = 1024 + 8. Blocks [0,1024): 16 rows each (4/wave). Blocks [1024,1032): SE.
__global__ __launch_bounds__(256) void k3(
    const float* __restrict__ gx, const float* __restrict__ tx,
    const float* __restrict__ px, const float* __restrict__ avgp,
    const float* __restrict__ gb,
    const float* __restrict__ se1w, const float* __restrict__ se1b,
    const float* __restrict__ se2w, const float* __restrict__ se2b,
    const float* __restrict__ Ww, const float* __restrict__ Wb,
    const float* __restrict__ gamma, const float* __restrict__ beta,
    const float* __restrict__ mean, const float* __restrict__ var,
    float* __restrict__ y, float* __restrict__ Ac, float* __restrict__ Dc)
{
    __shared__ float smem[4096];   // 16 KB, shared by both paths
    int tid = threadIdx.x;

    if (blockIdx.x >= 1024) {
        // ---- SE / affine for sample b ----
        int b = blockIdx.x - 1024;
        float* sA = smem;          // 512
        float* sP = smem + 512;    // 32*8
        float* sM = smem + 768;    // 32
        for (int c = tid; c < CC; c += 256) {
            const float* apt = avgp + (size_t)(b * CC + c) * 8;
            float ssum = 0.f;
            #pragma unroll
            for (int k = 0; k < 8; ++k) ssum += apt[k];
            sA[c] = ssum * (1.0f / NN);
        }
        __syncthreads();
        {
            int m = tid >> 3, sub = tid & 7;
            const float* w1 = se1w + m * CC + sub * 64;
            const float* a1 = sA + sub * 64;
            float ssum = 0.f;
            #pragma unroll
            for (int k = 0; k < 64; ++k) ssum = fmaf(a1[k], w1[k], ssum);
            sP[m * 8 + sub] = ssum;
        }
        __syncthreads();
        if (tid < SEM) {
            float t = 0.f;
            #pragma unroll
            for (int k = 0; k < 8; ++k) t += sP[tid * 8 + k];
            sM[tid] = fmaxf(t + se1b[tid], 0.f);
        }
        __syncthreads();
        float gbv = gb[0];
        for (int c = tid; c < CC; c += 256) {
            float s2 = 0.f;
            #pragma unroll
            for (int m = 0; m < SEM; ++m) s2 = fmaf(sM[m], se2w[c * SEM + m], s2);
            s2 += se2b[c];
            float wcw = 1.f / (1.f + __expf(-s2));
            float inv = gamma[c] * rsqrtf(var[c] + BN_EPS);
            float A = wcw * Ww[c] * inv;
            Ac[b * CC + c] = A;
            Dc[b * CC + c] = wcw * ((Wb[c] - mean[c]) * inv + beta[c]) + A * gbv;
        }
        return;
    }

    // ---- softmax path ----
    float* spx = smem;           // 2048 floats
    float* sgx = smem + 2048;    // 2048 floats
    int b  = blockIdx.x >> 7;
    int i0 = (blockIdx.x & 127) << 4;
    {
        const float4* pxr = reinterpret_cast<const float4*>(px + (size_t)b * NN);
        const float4* gxr = reinterpret_cast<const float4*>(gx + (size_t)b * NN);
        float4* spx4 = reinterpret_cast<float4*>(spx);
        float4* sgx4 = reinterpret_cast<float4*>(sgx);
        #pragma unroll
        for (int w = 0; w < 2; ++w) {
            int idx = w * 256 + tid;
            spx4[idx] = pxr[idx];
            sgx4[idx] = gxr[idx];
        }
    }
    __syncthreads();

    int wave = tid >> 6, lane = tid & 63;
    int r0 = i0 + wave * 4;
    float t0 = tx[b * NN + r0 + 0] * LOG2E;
    float t1 = tx[b * NN + r0 + 1] * LOG2E;
    float t2 = tx[b * NN + r0 + 2] * LOG2E;
    float t3 = tx[b * NN + r0 + 3] * LOG2E;
    float s0 = 0.f, g0 = 0.f, s1 = 0.f, g1 = 0.f;
    float s2 = 0.f, g2 = 0.f, s3 = 0.f, g3 = 0.f;
    const float2* spx2 = reinterpret_cast<const float2*>(spx);
    const float2* sgx2 = reinterpret_cast<const float2*>(sgx);
    #pragma unroll 4
    for (int it = 0; it < 16; ++it) {
        int jj = it * 64 + lane;
        float2 xv = spx2[jj];
        float2 gv = sgx2[jj];
        float e0a = exp2f(fminf(t0 * xv.x, 115.f)), e0b = exp2f(fminf(t0 * xv.y, 115.f));
        float e1a = exp2f(fminf(t1 * xv.x, 115.f)), e1b = exp2f(fminf(t1 * xv.y, 115.f));
        float e2a = exp2f(fminf(t2 * xv.x, 115.f)), e2b = exp2f(fminf(t2 * xv.y, 115.f));
        float e3a = exp2f(fminf(t3 * xv.x, 115.f)), e3b = exp2f(fminf(t3 * xv.y, 115.f));
        s0 += e0a + e0b; g0 = fmaf(e0a, gv.x, fmaf(e0b, gv.y, g0));
        s1 += e1a + e1b; g1 = fmaf(e1a, gv.x, fmaf(e1b, gv.y, g1));
        s2 += e2a + e2b; g2 = fmaf(e2a, gv.x, fmaf(e2b, gv.y, g2));
        s3 += e3a + e3b; g3 = fmaf(e3a, gv.x, fmaf(e3b, gv.y, g3));
    }
    for (int o = 32; o > 0; o >>= 1) {
        s0 += __shfl_down(s0, o); g0 += __shfl_down(g0, o);
        s1 += __shfl_down(s1, o); g1 += __shfl_down(g1, o);
        s2 += __shfl_down(s2, o); g2 += __shfl_down(g2, o);
        s3 += __shfl_down(s3, o); g3 += __shfl_down(g3, o);
    }
    if (lane == 0) {
        y[b * NN + r0 + 0] = g0 / s0;
        y[b * NN + r0 + 1] = g1 / s1;
        y[b * NN + r0 + 2] = g2 / s2;
        y[b * NN + r0 + 3] = g3 / s3;
    }
}

// ---------------- K4: epilogue out = A*y + D + x ----------------
// grid = 4096 blocks: one (b,c) row each; thread: 2 float4.
__global__ __launch_bounds__(256) void k4(
    const float* __restrict__ x, const float* __restrict__ y,
    const float* __restrict__ Ac, const float* __restrict__ Dc,
    float* __restrict__ out)
{
    int bc = blockIdx.x;
    int b = bc >> 9;
    float a = Ac[bc], d = Dc[bc];
    const float4* x4 = reinterpret_cast<const float4*>(x) + (size_t)bc * (NN / 4);
    const float4* y4 = reinterpret_cast<const float4*>(y) + (size_t)b * (NN / 4);
    float4* o4 = reinterpret_cast<float4*>(out) + (size_t)bc * (NN / 4);
    int tid = threadIdx.x;
    #pragma unroll
    for (int k = 0; k < 2; ++k) {
        int idx = k * 256 + tid;
        float4 xv = x4[idx], yv = y4[idx], ov;
        ov.x = fmaf(a, yv.x, d) + xv.x;
        ov.y = fmaf(a, yv.y, d) + xv.y;
        ov.z = fmaf(a, yv.z, d) + xv.z;
        ov.w = fmaf(a, yv.w, d) + xv.w;
        o4[idx] = ov;
    }
}

extern "C" void kernel_launch(void* const* d_in, const int* in_sizes, int n_in,
                              void* d_out, int out_size, void* d_ws, size_t ws_size,
                              hipStream_t stream) {
    const float* x    = (const float*)d_in[0];
    const float* gw   = (const float*)d_in[1];
    const float* gb   = (const float*)d_in[2];
    const float* tw   = (const float*)d_in[3];
    const float* tb   = (const float*)d_in[4];
    const float* pw   = (const float*)d_in[5];
    const float* pb   = (const float*)d_in[6];
    const float* Ww   = (const float*)d_in[7];
    const float* Wb   = (const float*)d_in[8];
    const float* gam  = (const float*)d_in[9];
    const float* bet  = (const float*)d_in[10];
    const float* mu   = (const float*)d_in[11];
    const float* var  = (const float*)d_in[12];
    const float* se1w = (const float*)d_in[13];
    const float* se1b = (const float*)d_in[14];
    const float* se2w = (const float*)d_in[15];
    const float* se2b = (const float*)d_in[16];

    float* ws   = (float*)d_ws;
    float* pp   = ws; ws += 3 * (size_t)KARR;
    float* avgp = ws; ws += BB * CC * 8;
    float* gx   = ws; ws += BB * NN;
    float* tx   = ws; ws += BB * NN;
    float* px   = ws; ws += BB * NN;
    float* y    = ws; ws += BB * NN;
    float* Ac   = ws; ws += BB * CC;
    float* Dc   = ws; ws += BB * CC;
    float* out  = (float*)d_out;

    k1<<<BB * NG * 2, 256, 0, stream>>>(x, gw, tw, pw, pp, avgp);
    k2<<<BB * 3 * 8, 256, 0, stream>>>(pp, tb, pb, gx, tx, px);
    k3<<<1024 + BB, 256, 0, stream>>>(gx, tx, px, avgp, gb, se1w, se1b, se2w, se2b,
                                      Ww, Wb, gam, bet, mu, var, y, Ac, Dc);
    k4<<<BB * CC, 256, 0, stream>>>(x, y, Ac, Dc, out);
}